// Round 6
// baseline (422.063 us; speedup 1.0000x reference)
//
#include <hip/hip_runtime.h>

#define NN 100000
#define NE 1200000
#define NG 512
#define NSEG (3 * NN)
#define CHUNK 1024
#define NCHUNK ((NSEG + CHUNK - 1) / CHUNK)

// ---- workspace layout (bytes), all 16B-aligned ----
static constexpr size_t AGG_OFF   = 0;                                  // 3*NN*64 f32
static constexpr size_t AGG_BYTES = (size_t)NSEG * 64 * 4;              // 76,800,000
static constexpr size_t CUR_OFF   = AGG_OFF + AGG_BYTES;                // NSEG ints (hist -> cursor)
static constexpr size_t START_OFF = CUR_OFF + (size_t)NSEG * 4;         // NSEG ints
static constexpr size_t CSUM_OFF  = START_OFF + (size_t)NSEG * 4;       // NCHUNK ints
static constexpr size_t ESRC_OFF  = CSUM_OFF + 4096;                    // NE ints
static constexpr size_t POOL_OFF  = ESRC_OFF + (size_t)NE * 4;          // NG*64 f32
static constexpr size_t H0_OFF    = POOL_OFF + (size_t)NG * 64 * 4;     // NN*32 f32
static constexpr size_t H1_OFF    = H0_OFF + (size_t)NN * 32 * 4;       // NN*64 f32
static constexpr size_t H2_OFF    = H1_OFF + (size_t)NN * 64 * 4;       // NN*64 f32

// async global->LDS, 16B per lane; LDS dest = wave-uniform base + lane*16
__device__ __forceinline__ void async_copy16(float* lds, const float* g) {
    __builtin_amdgcn_global_load_lds(
        (const __attribute__((address_space(1))) void*)g,
        (__attribute__((address_space(3))) void*)lds, 16, 0, 0);
}

// ---- node embedding + pre MLP: h0[n][32] = relu(concat(se[x0],ce[x1]) @ pre_w + pre_b)
__global__ __launch_bounds__(256)
void k_embed_pre(const int* __restrict__ x, const float* __restrict__ se,
                 const float* __restrict__ ce, const float* __restrict__ pw,
                 const float* __restrict__ pb, float* __restrict__ h0) {
    __shared__ float sW[16 * 32];
    __shared__ float sB[32];
    for (int i = threadIdx.x; i < 512; i += blockDim.x) sW[i] = pw[i];
    if (threadIdx.x < 32) sB[threadIdx.x] = pb[threadIdx.x];
    __syncthreads();
    int n = blockIdx.x * blockDim.x + threadIdx.x;
    if (n >= NN) return;
    int si = x[2 * n], ci = x[2 * n + 1];
    float in[16];
#pragma unroll
    for (int k = 0; k < 8; k++) in[k] = se[si * 8 + k];
#pragma unroll
    for (int k = 0; k < 8; k++) in[8 + k] = ce[ci * 8 + k];
    float acc[32];
#pragma unroll
    for (int j = 0; j < 32; j++) acc[j] = sB[j];
#pragma unroll
    for (int k = 0; k < 16; k++) {
        float hv = in[k];
#pragma unroll
        for (int j = 0; j < 32; j++) acc[j] += hv * sW[k * 32 + j];
    }
    float* o = h0 + (size_t)n * 32;
#pragma unroll
    for (int j = 0; j < 32; j += 4) {
        float4 v = make_float4(fmaxf(acc[j], 0.f), fmaxf(acc[j + 1], 0.f),
                               fmaxf(acc[j + 2], 0.f), fmaxf(acc[j + 3], 0.f));
        *(float4*)(o + j) = v;
    }
}

// ---- histogram per (rel,dst) segment (into cur[], int atomics)
__global__ __launch_bounds__(256)
void k_count(const int* __restrict__ ei, const int* __restrict__ et, int* __restrict__ hist) {
    int e = blockIdx.x * blockDim.x + threadIdx.x;
    if (e >= NE) return;
    int d = ei[NE + e];
    int r = et[e];
    atomicAdd(&hist[r * NN + d], 1);
}

// ---- scan pass 1: per-chunk sums
__global__ __launch_bounds__(256)
void k_chunksum(const int* __restrict__ hist, int* __restrict__ csum) {
    __shared__ int s[256];
    int b = blockIdx.x, t = threadIdx.x;
    int base = b * CHUNK + t * 4;
    int sum = 0;
#pragma unroll
    for (int k = 0; k < 4; k++) {
        int i = base + k;
        if (i < NSEG) sum += hist[i];
    }
    s[t] = sum;
    __syncthreads();
    for (int off = 128; off > 0; off >>= 1) {
        if (t < off) s[t] += s[t + off];
        __syncthreads();
    }
    if (t == 0) csum[b] = s[0];
}

// ---- scan pass 2: exclusive scan of chunk sums (one 512-thread block)
__global__ __launch_bounds__(512)
void k_chunkscan(int* __restrict__ csum) {
    __shared__ int s[512];
    int t = threadIdx.x;
    int v = (t < NCHUNK) ? csum[t] : 0;
    s[t] = v;
    __syncthreads();
    for (int off = 1; off < 512; off <<= 1) {
        int x = (t >= off) ? s[t - off] : 0;
        __syncthreads();
        s[t] += x;
        __syncthreads();
    }
    if (t < NCHUNK) csum[t] = s[t] - v;   // exclusive
}

// ---- scan pass 3: local exclusive scan; writes start[] and re-inits cur[] (cursor)
__global__ __launch_bounds__(256)
void k_localscan(int* __restrict__ hist_cur, const int* __restrict__ csum,
                 int* __restrict__ start) {
    __shared__ int s[256];
    int b = blockIdx.x, t = threadIdx.x;
    int base = b * CHUNK + t * 4;
    int v[4];
    int s4 = 0;
#pragma unroll
    for (int k = 0; k < 4; k++) {
        int i = base + k;
        v[k] = (i < NSEG) ? hist_cur[i] : 0;
        s4 += v[k];
    }
    s[t] = s4;
    __syncthreads();
    for (int off = 1; off < 256; off <<= 1) {
        int x = (t >= off) ? s[t - off] : 0;
        __syncthreads();
        s[t] += x;
        __syncthreads();
    }
    int excl = s[t] - s4 + csum[b];
#pragma unroll
    for (int k = 0; k < 4; k++) {
        int i = base + k;
        if (i < NSEG) {
            start[i] = excl;
            hist_cur[i] = excl;  // cursor for fill
        }
        excl += v[k];
    }
}

// ---- fill CSR edge array (src ids), int-atomic cursors
__global__ __launch_bounds__(256)
void k_fill(const int* __restrict__ ei, const int* __restrict__ et,
            int* __restrict__ cur, int* __restrict__ esrc) {
    int e = blockIdx.x * blockDim.x + threadIdx.x;
    if (e >= NE) return;
    int s = ei[e], d = ei[NE + e], r = et[e];
    int pos = atomicAdd(&cur[r * NN + d], 1);
    esrc[pos] = s;
}

// ---- gather-aggregate: agg[seg][0:C] = MEAN_{edges in seg} h[src][0:C]
template <int C>
__global__ __launch_bounds__(256)
void k_gather(const int* __restrict__ start, const int* __restrict__ cur,
              const int* __restrict__ esrc, const float* __restrict__ h,
              float* __restrict__ agg) {
    constexpr int P = C / 4;
    int tid = blockIdx.x * blockDim.x + threadIdx.x;
    int seg = tid / P;
    int p = tid % P;
    if (seg >= NSEG) return;
    int st = start[seg], en = cur[seg];
    float4 acc = make_float4(0.f, 0.f, 0.f, 0.f);
    int i = st;
    for (; i + 4 <= en; i += 4) {
        int s0 = esrc[i + 0], s1 = esrc[i + 1], s2 = esrc[i + 2], s3 = esrc[i + 3];
        float4 v0 = *(const float4*)(h + (size_t)s0 * C + p * 4);
        float4 v1 = *(const float4*)(h + (size_t)s1 * C + p * 4);
        float4 v2 = *(const float4*)(h + (size_t)s2 * C + p * 4);
        float4 v3 = *(const float4*)(h + (size_t)s3 * C + p * 4);
        acc.x += (v0.x + v1.x) + (v2.x + v3.x);
        acc.y += (v0.y + v1.y) + (v2.y + v3.y);
        acc.z += (v0.z + v1.z) + (v2.z + v3.z);
        acc.w += (v0.w + v1.w) + (v2.w + v3.w);
    }
    for (; i < en; i++) {
        int s = esrc[i];
        float4 v = *(const float4*)(h + (size_t)s * C + p * 4);
        acc.x += v.x; acc.y += v.y; acc.z += v.z; acc.w += v.w;
    }
    int c = en - st;
    float inv = 1.f / (float)(c > 1 ? c : 1);
    acc.x *= inv; acc.y *= inv; acc.z *= inv; acc.w *= inv;
    *(float4*)(agg + (size_t)seg * C + p * 4) = acc;
}

// ---- combine: out[NN][64] = relu(concat(h_in, mean_r) @ concat(root, W_r) + b)
// 256 threads = 4 waves, BN=128 nodes; thread = 4 nodes (stride 32) x 8 cols.
// Inputs staged via global_load_lds into XOR-swizzled linear LDS (conflict-free
// ds_read_b128); weights read straight from global (L1/L2-resident, 8-lane
// same-address coalescing) -> DS pipe carries only 256 reads/wave.
template <int CIN>
__global__ __launch_bounds__(256, 1)
void k_combine_t(const float* __restrict__ h_in, const float* __restrict__ agg,
                 const float* __restrict__ root, const float* __restrict__ w,
                 const float* __restrict__ bias, float* __restrict__ h_out) {
    constexpr int BN = 128;
    constexpr int F4R = CIN / 4;                 // float4s per input row (8 or 16)
    constexpr int TOTF4 = BN * F4R;              // 1024 or 2048
    constexpr int ISSUES = TOTF4 / 256;          // global_load_lds per thread (4 or 8)
    __shared__ float4 sIN[TOTF4];

    const int tid = threadIdx.x;
    const int lane = tid & 63;
    const int wave = tid >> 6;                   // 0..3
    const int cg = tid & 7;                      // col group -> cols 8*cg..8*cg+7
    const int ng = tid >> 3;                     // 0..31; node rows ng + m*32
    const int n0 = blockIdx.x * BN;

    float4 acc[4][2];
    {
        const float4 b0 = *(const float4*)(bias + cg * 8);
        const float4 b1 = *(const float4*)(bias + cg * 8 + 4);
#pragma unroll
        for (int m = 0; m < 4; m++) { acc[m][0] = b0; acc[m][1] = b1; }
    }

    for (int kb = 0; kb < 4; kb++) {
        const float* __restrict__ wsrc = (kb == 0) ? root : (w + (size_t)(kb - 1) * CIN * 64);
        const float* __restrict__ isrc = (kb == 0) ? h_in : (agg + (size_t)(kb - 1) * NN * CIN);
        // stage inputs: LDS slot F holds global f4 (row, j ^ (row&7))  [involution]
#pragma unroll
        for (int i = 0; i < ISSUES; i++) {
            int F = (wave * ISSUES + i) * 64 + lane;
            int row = F / F4R;
            int j = F % F4R;
            int js = j ^ (row & 7);
            const float* src = isrc + (size_t)(n0 + row) * CIN + js * 4;
            async_copy16((float*)&sIN[(wave * ISSUES + i) * 64], src);
        }
        __syncthreads();   // drains vmcnt (incl. global_load_lds) then barrier
#pragma unroll 2
        for (int ks = 0; ks < F4R; ks++) {       // k = 4*ks
            float4 w0[4], w1[4];
#pragma unroll
            for (int i = 0; i < 4; i++) {
                w0[i] = *(const float4*)(wsrc + (4 * ks + i) * 64 + cg * 8);
                w1[i] = *(const float4*)(wsrc + (4 * ks + i) * 64 + cg * 8 + 4);
            }
#pragma unroll
            for (int m = 0; m < 4; m++) {
                int row = ng + m * 32;
                float4 iv = sIN[row * F4R + (ks ^ (row & 7))];
                acc[m][0].x += iv.x * w0[0].x + iv.y * w0[1].x + iv.z * w0[2].x + iv.w * w0[3].x;
                acc[m][0].y += iv.x * w0[0].y + iv.y * w0[1].y + iv.z * w0[2].y + iv.w * w0[3].y;
                acc[m][0].z += iv.x * w0[0].z + iv.y * w0[1].z + iv.z * w0[2].z + iv.w * w0[3].z;
                acc[m][0].w += iv.x * w0[0].w + iv.y * w0[1].w + iv.z * w0[2].w + iv.w * w0[3].w;
                acc[m][1].x += iv.x * w1[0].x + iv.y * w1[1].x + iv.z * w1[2].x + iv.w * w1[3].x;
                acc[m][1].y += iv.x * w1[0].y + iv.y * w1[1].y + iv.z * w1[2].y + iv.w * w1[3].y;
                acc[m][1].z += iv.x * w1[0].z + iv.y * w1[1].z + iv.z * w1[2].z + iv.w * w1[3].z;
                acc[m][1].w += iv.x * w1[0].w + iv.y * w1[1].w + iv.z * w1[2].w + iv.w * w1[3].w;
            }
        }
        if (kb < 3) __syncthreads();
    }
    // write out with relu
#pragma unroll
    for (int m = 0; m < 4; m++) {
        int n = n0 + ng + m * 32;
        if (n < NN) {
            float* o = h_out + (size_t)n * 64 + cg * 8;
            float4 r0v = make_float4(fmaxf(acc[m][0].x, 0.f), fmaxf(acc[m][0].y, 0.f),
                                     fmaxf(acc[m][0].z, 0.f), fmaxf(acc[m][0].w, 0.f));
            float4 r1v = make_float4(fmaxf(acc[m][1].x, 0.f), fmaxf(acc[m][1].y, 0.f),
                                     fmaxf(acc[m][1].z, 0.f), fmaxf(acc[m][1].w, 0.f));
            *(float4*)o = r0v;
            *(float4*)(o + 4) = r1v;
        }
    }
}

// ---- mean pool via binary search on sorted batch (no atomics); writes mean directly
__global__ __launch_bounds__(256)
void k_pool(const float* __restrict__ h, const int* __restrict__ batch,
            float* __restrict__ pool) {
    int g = blockIdx.x;
    auto lb = [&](int v) {
        int lo = 0, hi = NN;
        while (lo < hi) {
            int m = (lo + hi) >> 1;
            if (batch[m] < v) lo = m + 1; else hi = m;
        }
        return lo;
    };
    int st = lb(g), en = lb(g + 1);
    int col = threadIdx.x & 63, chunk = threadIdx.x >> 6;
    float acc = 0.f;
    for (int n = st + chunk; n < en; n += 4) acc += h[(size_t)n * 64 + col];
    __shared__ float s[256];
    s[threadIdx.x] = acc;
    __syncthreads();
    if (chunk == 0) {
        float tot = s[col] + s[64 + col] + s[128 + col] + s[192 + col];
        int c = en - st;
        pool[g * 64 + col] = tot / (float)(c > 1 ? c : 1);
    }
}

// ---- classifier: out[g][j] = cls_b[j] + pool[g] @ cls_w[:,j]   (pool already mean)
__global__ __launch_bounds__(256)
void k_final(const float* __restrict__ pool, const float* __restrict__ cw,
             const float* __restrict__ cb, float* __restrict__ out) {
    int t = blockIdx.x * blockDim.x + threadIdx.x;
    if (t >= NG * 10) return;
    int g = t / 10, j = t % 10;
    float acc = 0.f;
#pragma unroll
    for (int k = 0; k < 64; k++) acc += pool[g * 64 + k] * cw[k * 10 + j];
    out[t] = cb[j] + acc;
}

extern "C" void kernel_launch(void* const* d_in, const int* in_sizes, int n_in,
                              void* d_out, int out_size, void* d_ws, size_t ws_size,
                              hipStream_t stream) {
    const int* x      = (const int*)d_in[0];
    const int* ei     = (const int*)d_in[1];
    const int* et     = (const int*)d_in[2];
    const int* batch  = (const int*)d_in[3];
    const float* se   = (const float*)d_in[4];
    const float* ce   = (const float*)d_in[5];
    const float* pw   = (const float*)d_in[6];
    const float* pb   = (const float*)d_in[7];
    const float* w1   = (const float*)d_in[8];
    const float* root1= (const float*)d_in[9];
    const float* b1   = (const float*)d_in[10];
    const float* w2   = (const float*)d_in[11];
    const float* root2= (const float*)d_in[12];
    const float* b2   = (const float*)d_in[13];
    const float* cw   = (const float*)d_in[14];
    const float* cb   = (const float*)d_in[15];
    float* out = (float*)d_out;

    char* ws = (char*)d_ws;
    float* agg   = (float*)(ws + AGG_OFF);
    int*   cur   = (int*)(ws + CUR_OFF);     // histogram, then cursor (== segment end after fill)
    int*   start = (int*)(ws + START_OFF);
    int*   csum  = (int*)(ws + CSUM_OFF);
    int*   esrc  = (int*)(ws + ESRC_OFF);
    float* pool  = (float*)(ws + POOL_OFF);
    float* h0    = (float*)(ws + H0_OFF);
    float* h1    = (float*)(ws + H1_OFF);
    float* h2    = (float*)(ws + H2_OFF);

    // zero the histogram only
    hipMemsetAsync(cur, 0, (size_t)NSEG * 4, stream);

    k_embed_pre<<<(NN + 255) / 256, 256, 0, stream>>>(x, se, ce, pw, pb, h0);

    // CSR build
    k_count<<<(NE + 255) / 256, 256, 0, stream>>>(ei, et, cur);
    k_chunksum<<<NCHUNK, 256, 0, stream>>>(cur, csum);
    k_chunkscan<<<1, 512, 0, stream>>>(csum);
    k_localscan<<<NCHUNK, 256, 0, stream>>>(cur, csum, start);
    k_fill<<<(NE + 255) / 256, 256, 0, stream>>>(ei, et, cur, esrc);

    // layer 1
    k_gather<32><<<(NSEG * 8 + 255) / 256, 256, 0, stream>>>(start, cur, esrc, h0, agg);
    k_combine_t<32><<<(NN + 127) / 128, 256, 0, stream>>>(h0, agg, root1, w1, b1, h1);

    // layer 2
    k_gather<64><<<(NSEG * 16 + 255) / 256, 256, 0, stream>>>(start, cur, esrc, h1, agg);
    k_combine_t<64><<<(NN + 127) / 128, 256, 0, stream>>>(h1, agg, root2, w2, b2, h2);

    // pooling + classifier
    k_pool<<<NG, 256, 0, stream>>>(h2, batch, pool);
    k_final<<<(NG * 10 + 255) / 256, 256, 0, stream>>>(pool, cw, cb, out);
}

// Round 7
// 310.095 us; speedup vs baseline: 1.3611x; 1.3611x over previous
//
#include <hip/hip_runtime.h>

#define NN 100000
#define NE 1200000
#define NG 512
#define NSEG (3 * NN)
#define CHUNK 1024
#define NCHUNK ((NSEG + CHUNK - 1) / CHUNK)

typedef __bf16 bf16x8 __attribute__((ext_vector_type(8)));
typedef float f32x4 __attribute__((ext_vector_type(4)));

// ---- workspace layout (bytes), all 16B-aligned ----
static constexpr size_t AGG_OFF   = 0;                                  // 3*NN*64 f32
static constexpr size_t AGG_BYTES = (size_t)NSEG * 64 * 4;              // 76,800,000
static constexpr size_t CUR_OFF   = AGG_OFF + AGG_BYTES;                // NSEG ints (hist -> cursor)
static constexpr size_t START_OFF = CUR_OFF + (size_t)NSEG * 4;         // NSEG ints
static constexpr size_t CSUM_OFF  = START_OFF + (size_t)NSEG * 4;       // NCHUNK ints
static constexpr size_t ESRC_OFF  = CSUM_OFF + 4096;                    // NE ints
static constexpr size_t POOL_OFF  = ESRC_OFF + (size_t)NE * 4;          // NG*64 f32
static constexpr size_t H0_OFF    = POOL_OFF + (size_t)NG * 64 * 4;     // NN*32 f32
static constexpr size_t H1_OFF    = H0_OFF + (size_t)NN * 32 * 4;       // NN*64 f32
static constexpr size_t H2_OFF    = H1_OFF + (size_t)NN * 64 * 4;       // NN*64 f32
static constexpr size_t WT1H_OFF  = H2_OFF + (size_t)NN * 64 * 4;       // 64*128 bf16
static constexpr size_t WT1L_OFF  = WT1H_OFF + 64 * 128 * 2;
static constexpr size_t WT2H_OFF  = WT1L_OFF + 64 * 128 * 2;            // 64*256 bf16
static constexpr size_t WT2L_OFF  = WT2H_OFF + 64 * 256 * 2;

// async global->LDS, 16B per lane; LDS dest = wave-uniform base + lane*16
__device__ __forceinline__ void async_copy16(void* lds, const void* g) {
    __builtin_amdgcn_global_load_lds(
        (const __attribute__((address_space(1))) void*)g,
        (__attribute__((address_space(3))) void*)lds, 16, 0, 0);
}

// ---- node embedding + pre MLP: h0[n][32] = relu(concat(se[x0],ce[x1]) @ pre_w + pre_b)
__global__ __launch_bounds__(256)
void k_embed_pre(const int* __restrict__ x, const float* __restrict__ se,
                 const float* __restrict__ ce, const float* __restrict__ pw,
                 const float* __restrict__ pb, float* __restrict__ h0) {
    __shared__ float sW[16 * 32];
    __shared__ float sB[32];
    for (int i = threadIdx.x; i < 512; i += blockDim.x) sW[i] = pw[i];
    if (threadIdx.x < 32) sB[threadIdx.x] = pb[threadIdx.x];
    __syncthreads();
    int n = blockIdx.x * blockDim.x + threadIdx.x;
    if (n >= NN) return;
    int si = x[2 * n], ci = x[2 * n + 1];
    float in[16];
#pragma unroll
    for (int k = 0; k < 8; k++) in[k] = se[si * 8 + k];
#pragma unroll
    for (int k = 0; k < 8; k++) in[8 + k] = ce[ci * 8 + k];
    float acc[32];
#pragma unroll
    for (int j = 0; j < 32; j++) acc[j] = sB[j];
#pragma unroll
    for (int k = 0; k < 16; k++) {
        float hv = in[k];
#pragma unroll
        for (int j = 0; j < 32; j++) acc[j] += hv * sW[k * 32 + j];
    }
    float* o = h0 + (size_t)n * 32;
#pragma unroll
    for (int j = 0; j < 32; j += 4) {
        float4 v = make_float4(fmaxf(acc[j], 0.f), fmaxf(acc[j + 1], 0.f),
                               fmaxf(acc[j + 2], 0.f), fmaxf(acc[j + 3], 0.f));
        *(float4*)(o + j) = v;
    }
}

// ---- weight prep: Wt_hi/lo[j][k] (bf16, transposed, split) from [root | W_r] (fp32 [K][64])
__global__ __launch_bounds__(256)
void k_prepw(const float* __restrict__ root, const float* __restrict__ w,
             __bf16* __restrict__ wh, __bf16* __restrict__ wl, int cin) {
    int kt = 4 * cin;
    int t = blockIdx.x * 256 + threadIdx.x;
    if (t >= 64 * kt) return;
    int j = t / kt, k = t % kt;
    int sidx = k / cin, kk = k % cin;
    float v = (sidx == 0) ? root[kk * 64 + j]
                          : w[((size_t)(sidx - 1) * cin + kk) * 64 + j];
    __bf16 h = (__bf16)v;
    wh[t] = h;
    wl[t] = (__bf16)(v - (float)h);
}

// ---- histogram per (rel,dst) segment (into cur[], int atomics)
__global__ __launch_bounds__(256)
void k_count(const int* __restrict__ ei, const int* __restrict__ et, int* __restrict__ hist) {
    int e = blockIdx.x * blockDim.x + threadIdx.x;
    if (e >= NE) return;
    int d = ei[NE + e];
    int r = et[e];
    atomicAdd(&hist[r * NN + d], 1);
}

// ---- scan pass 1: per-chunk sums
__global__ __launch_bounds__(256)
void k_chunksum(const int* __restrict__ hist, int* __restrict__ csum) {
    __shared__ int s[256];
    int b = blockIdx.x, t = threadIdx.x;
    int base = b * CHUNK + t * 4;
    int sum = 0;
#pragma unroll
    for (int k = 0; k < 4; k++) {
        int i = base + k;
        if (i < NSEG) sum += hist[i];
    }
    s[t] = sum;
    __syncthreads();
    for (int off = 128; off > 0; off >>= 1) {
        if (t < off) s[t] += s[t + off];
        __syncthreads();
    }
    if (t == 0) csum[b] = s[0];
}

// ---- scan pass 2: exclusive scan of chunk sums (one 512-thread block)
__global__ __launch_bounds__(512)
void k_chunkscan(int* __restrict__ csum) {
    __shared__ int s[512];
    int t = threadIdx.x;
    int v = (t < NCHUNK) ? csum[t] : 0;
    s[t] = v;
    __syncthreads();
    for (int off = 1; off < 512; off <<= 1) {
        int x = (t >= off) ? s[t - off] : 0;
        __syncthreads();
        s[t] += x;
        __syncthreads();
    }
    if (t < NCHUNK) csum[t] = s[t] - v;   // exclusive
}

// ---- scan pass 3: local exclusive scan; writes start[] and re-inits cur[] (cursor)
__global__ __launch_bounds__(256)
void k_localscan(int* __restrict__ hist_cur, const int* __restrict__ csum,
                 int* __restrict__ start) {
    __shared__ int s[256];
    int b = blockIdx.x, t = threadIdx.x;
    int base = b * CHUNK + t * 4;
    int v[4];
    int s4 = 0;
#pragma unroll
    for (int k = 0; k < 4; k++) {
        int i = base + k;
        v[k] = (i < NSEG) ? hist_cur[i] : 0;
        s4 += v[k];
    }
    s[t] = s4;
    __syncthreads();
    for (int off = 1; off < 256; off <<= 1) {
        int x = (t >= off) ? s[t - off] : 0;
        __syncthreads();
        s[t] += x;
        __syncthreads();
    }
    int excl = s[t] - s4 + csum[b];
#pragma unroll
    for (int k = 0; k < 4; k++) {
        int i = base + k;
        if (i < NSEG) {
            start[i] = excl;
            hist_cur[i] = excl;  // cursor for fill
        }
        excl += v[k];
    }
}

// ---- fill CSR edge array (src ids), int-atomic cursors
__global__ __launch_bounds__(256)
void k_fill(const int* __restrict__ ei, const int* __restrict__ et,
            int* __restrict__ cur, int* __restrict__ esrc) {
    int e = blockIdx.x * blockDim.x + threadIdx.x;
    if (e >= NE) return;
    int s = ei[e], d = ei[NE + e], r = et[e];
    int pos = atomicAdd(&cur[r * NN + d], 1);
    esrc[pos] = s;
}

// ---- gather-aggregate: agg[seg][0:C] = MEAN_{edges in seg} h[src][0:C]
template <int C>
__global__ __launch_bounds__(256)
void k_gather(const int* __restrict__ start, const int* __restrict__ cur,
              const int* __restrict__ esrc, const float* __restrict__ h,
              float* __restrict__ agg) {
    constexpr int P = C / 4;
    int tid = blockIdx.x * blockDim.x + threadIdx.x;
    int seg = tid / P;
    int p = tid % P;
    if (seg >= NSEG) return;
    int st = start[seg], en = cur[seg];
    float4 acc = make_float4(0.f, 0.f, 0.f, 0.f);
    int i = st;
    for (; i + 4 <= en; i += 4) {
        int s0 = esrc[i + 0], s1 = esrc[i + 1], s2 = esrc[i + 2], s3 = esrc[i + 3];
        float4 v0 = *(const float4*)(h + (size_t)s0 * C + p * 4);
        float4 v1 = *(const float4*)(h + (size_t)s1 * C + p * 4);
        float4 v2 = *(const float4*)(h + (size_t)s2 * C + p * 4);
        float4 v3 = *(const float4*)(h + (size_t)s3 * C + p * 4);
        acc.x += (v0.x + v1.x) + (v2.x + v3.x);
        acc.y += (v0.y + v1.y) + (v2.y + v3.y);
        acc.z += (v0.z + v1.z) + (v2.z + v3.z);
        acc.w += (v0.w + v1.w) + (v2.w + v3.w);
    }
    for (; i < en; i++) {
        int s = esrc[i];
        float4 v = *(const float4*)(h + (size_t)s * C + p * 4);
        acc.x += v.x; acc.y += v.y; acc.z += v.z; acc.w += v.w;
    }
    int c = en - st;
    float inv = 1.f / (float)(c > 1 ? c : 1);
    acc.x *= inv; acc.y *= inv; acc.z *= inv; acc.w *= inv;
    *(float4*)(agg + (size_t)seg * C + p * 4) = acc;
}

// split 8 fp32 -> hi/lo bf16x8 fragments (hi+lo represents x to ~2^-18 rel)
__device__ __forceinline__ void split8(float4 a0, float4 a1, bf16x8& hi, bf16x8& lo) {
    float v[8] = {a0.x, a0.y, a0.z, a0.w, a1.x, a1.y, a1.z, a1.w};
#pragma unroll
    for (int i = 0; i < 8; i++) {
        __bf16 h = (__bf16)v[i];
        hi[i] = h;
        lo[i] = (__bf16)(v[i] - (float)h);
    }
}

// ---- combine via split-bf16 MFMA:
// OUT[NN][64] = relu(concat(h_in, mean_r) @ concat(root, W_r) + b)
// block = 64 nodes, 4 waves; wave = 16 rows x 64 cols; K chunked by 64.
// A (inputs) staged fp32 in LDS, XOR-swizzled (slot ^= row&7); converted to
// hi/lo bf16 fragments in-register. B (weights) pre-split bf16, staged
// transposed [col][k], XOR-swizzled (oword ^= col&7). Both swizzles are
// both-sides involutions with linear global_load_lds dest (rule 21).
template <int CIN>
__global__ __launch_bounds__(256, 1)
void k_combine_m(const float* __restrict__ h_in, const float* __restrict__ agg,
                 const __bf16* __restrict__ wh, const __bf16* __restrict__ wl,
                 const float* __restrict__ bias, float* __restrict__ h_out) {
    constexpr int KT = 4 * CIN;          // 128 or 256
    constexpr int NCHK = KT / 64;        // 2 or 4 chunks of K=64
    __shared__ float sIN[64 * 64];       // 16 KB
    __shared__ __bf16 sWH[64 * 64];      // 8 KB
    __shared__ __bf16 sWL[64 * 64];      // 8 KB

    const int tid = threadIdx.x;
    const int wave = tid >> 6;
    const int lane = tid & 63;
    const int cA = lane & 15;            // A-row-in-tile / C-col-in-group
    const int kg = lane >> 4;            // k-group 0..3
    const int n0 = blockIdx.x * 64;

    f32x4 acc[4];
#pragma unroll
    for (int nb = 0; nb < 4; nb++) {
        float bv = bias[nb * 16 + cA];
        acc[nb][0] = bv; acc[nb][1] = bv; acc[nb][2] = bv; acc[nb][3] = bv;
    }

    for (int c = 0; c < NCHK; c++) {
        if (c) __syncthreads();
        // stage IN chunk: 1024 f4 slots; slot F holds orig f4 (row, j^(row&7))
#pragma unroll
        for (int i = 0; i < 4; i++) {
            int F = tid + i * 256;
            int row = F >> 4, j = F & 15;
            int jor = j ^ (row & 7);
            int n = n0 + row; if (n > NN - 1) n = NN - 1;
            const float* src;
            if (CIN == 64) {
                src = (c == 0 ? h_in + (size_t)n * 64
                              : agg + ((size_t)(c - 1) * NN + n) * 64) + jor * 4;
            } else {
                int sidx = 2 * c + (jor >> 3);
                int jj = jor & 7;
                src = (sidx == 0 ? h_in + (size_t)n * 32
                                 : agg + ((size_t)(sidx - 1) * NN + n) * 32) + jj * 4;
            }
            async_copy16(sIN + (size_t)F * 4, src);
        }
        // stage Wt chunk (hi & lo): 512 f4 slots each; slot F holds (col, s^(col&7))
#pragma unroll
        for (int i = 0; i < 2; i++) {
            int F = tid + i * 256;
            int col = F >> 3, s = F & 7;
            int sor = s ^ (col & 7);
            const __bf16* sh = wh + (size_t)col * KT + c * 64 + sor * 8;
            const __bf16* sl = wl + (size_t)col * KT + c * 64 + sor * 8;
            async_copy16(sWH + (size_t)F * 8, sh);
            async_copy16(sWL + (size_t)F * 8, sl);
        }
        __syncthreads();   // drains vmcnt (incl. global_load_lds) then barrier
        // compute: 2 K-steps of 32 per chunk
#pragma unroll
        for (int ks = 0; ks < 2; ks++) {
            const int rowL = wave * 16 + cA;
            const int jA = ks * 8 + kg * 2;
            float4 a0 = ((const float4*)sIN)[rowL * 16 + (jA ^ (rowL & 7))];
            float4 a1 = ((const float4*)sIN)[rowL * 16 + ((jA + 1) ^ (rowL & 7))];
            bf16x8 ah, al;
            split8(a0, a1, ah, al);
            const int k8 = ks * 4 + kg;
#pragma unroll
            for (int nb = 0; nb < 4; nb++) {
                const int col = nb * 16 + cA;
                const int bs = col * 8 + (k8 ^ (col & 7));
                bf16x8 bh = ((const bf16x8*)sWH)[bs];
                bf16x8 bl = ((const bf16x8*)sWL)[bs];
                acc[nb] = __builtin_amdgcn_mfma_f32_16x16x32_bf16(ah, bh, acc[nb], 0, 0, 0);
                acc[nb] = __builtin_amdgcn_mfma_f32_16x16x32_bf16(al, bh, acc[nb], 0, 0, 0);
                acc[nb] = __builtin_amdgcn_mfma_f32_16x16x32_bf16(ah, bl, acc[nb], 0, 0, 0);
                acc[nb] = __builtin_amdgcn_mfma_f32_16x16x32_bf16(al, bl, acc[nb], 0, 0, 0);
            }
        }
    }
    // store with relu: D row = 16*wave + kg*4 + r, col = 16*nb + cA
#pragma unroll
    for (int nb = 0; nb < 4; nb++) {
#pragma unroll
        for (int r = 0; r < 4; r++) {
            int n = n0 + wave * 16 + kg * 4 + r;
            if (n < NN)
                h_out[(size_t)n * 64 + nb * 16 + cA] = fmaxf(acc[nb][r], 0.f);
        }
    }
}

// ---- mean pool via binary search on sorted batch (no atomics); writes mean directly
__global__ __launch_bounds__(256)
void k_pool(const float* __restrict__ h, const int* __restrict__ batch,
            float* __restrict__ pool) {
    int g = blockIdx.x;
    auto lb = [&](int v) {
        int lo = 0, hi = NN;
        while (lo < hi) {
            int m = (lo + hi) >> 1;
            if (batch[m] < v) lo = m + 1; else hi = m;
        }
        return lo;
    };
    int st = lb(g), en = lb(g + 1);
    int col = threadIdx.x & 63, chunk = threadIdx.x >> 6;
    float acc = 0.f;
    for (int n = st + chunk; n < en; n += 4) acc += h[(size_t)n * 64 + col];
    __shared__ float s[256];
    s[threadIdx.x] = acc;
    __syncthreads();
    if (chunk == 0) {
        float tot = s[col] + s[64 + col] + s[128 + col] + s[192 + col];
        int c = en - st;
        pool[g * 64 + col] = tot / (float)(c > 1 ? c : 1);
    }
}

// ---- classifier: out[g][j] = cls_b[j] + pool[g] @ cls_w[:,j]   (pool already mean)
__global__ __launch_bounds__(256)
void k_final(const float* __restrict__ pool, const float* __restrict__ cw,
             const float* __restrict__ cb, float* __restrict__ out) {
    int t = blockIdx.x * blockDim.x + threadIdx.x;
    if (t >= NG * 10) return;
    int g = t / 10, j = t % 10;
    float acc = 0.f;
#pragma unroll
    for (int k = 0; k < 64; k++) acc += pool[g * 64 + k] * cw[k * 10 + j];
    out[t] = cb[j] + acc;
}

extern "C" void kernel_launch(void* const* d_in, const int* in_sizes, int n_in,
                              void* d_out, int out_size, void* d_ws, size_t ws_size,
                              hipStream_t stream) {
    const int* x      = (const int*)d_in[0];
    const int* ei     = (const int*)d_in[1];
    const int* et     = (const int*)d_in[2];
    const int* batch  = (const int*)d_in[3];
    const float* se   = (const float*)d_in[4];
    const float* ce   = (const float*)d_in[5];
    const float* pw   = (const float*)d_in[6];
    const float* pb   = (const float*)d_in[7];
    const float* w1   = (const float*)d_in[8];
    const float* root1= (const float*)d_in[9];
    const float* b1   = (const float*)d_in[10];
    const float* w2   = (const float*)d_in[11];
    const float* root2= (const float*)d_in[12];
    const float* b2   = (const float*)d_in[13];
    const float* cw   = (const float*)d_in[14];
    const float* cb   = (const float*)d_in[15];
    float* out = (float*)d_out;

    char* ws = (char*)d_ws;
    float* agg   = (float*)(ws + AGG_OFF);
    int*   cur   = (int*)(ws + CUR_OFF);     // histogram, then cursor (== segment end after fill)
    int*   start = (int*)(ws + START_OFF);
    int*   csum  = (int*)(ws + CSUM_OFF);
    int*   esrc  = (int*)(ws + ESRC_OFF);
    float* pool  = (float*)(ws + POOL_OFF);
    float* h0    = (float*)(ws + H0_OFF);
    float* h1    = (float*)(ws + H1_OFF);
    float* h2    = (float*)(ws + H2_OFF);
    __bf16* wt1h = (__bf16*)(ws + WT1H_OFF);
    __bf16* wt1l = (__bf16*)(ws + WT1L_OFF);
    __bf16* wt2h = (__bf16*)(ws + WT2H_OFF);
    __bf16* wt2l = (__bf16*)(ws + WT2L_OFF);

    // zero the histogram only
    hipMemsetAsync(cur, 0, (size_t)NSEG * 4, stream);

    k_embed_pre<<<(NN + 255) / 256, 256, 0, stream>>>(x, se, ce, pw, pb, h0);
    k_prepw<<<(64 * 128 + 255) / 256, 256, 0, stream>>>(root1, w1, wt1h, wt1l, 32);
    k_prepw<<<(64 * 256 + 255) / 256, 256, 0, stream>>>(root2, w2, wt2h, wt2l, 64);

    // CSR build
    k_count<<<(NE + 255) / 256, 256, 0, stream>>>(ei, et, cur);
    k_chunksum<<<NCHUNK, 256, 0, stream>>>(cur, csum);
    k_chunkscan<<<1, 512, 0, stream>>>(csum);
    k_localscan<<<NCHUNK, 256, 0, stream>>>(cur, csum, start);
    k_fill<<<(NE + 255) / 256, 256, 0, stream>>>(ei, et, cur, esrc);

    // layer 1
    k_gather<32><<<(NSEG * 8 + 255) / 256, 256, 0, stream>>>(start, cur, esrc, h0, agg);
    k_combine_m<32><<<(NN + 63) / 64, 256, 0, stream>>>(h0, agg, wt1h, wt1l, b1, h1);

    // layer 2
    k_gather<64><<<(NSEG * 16 + 255) / 256, 256, 0, stream>>>(start, cur, esrc, h1, agg);
    k_combine_m<64><<<(NN + 63) / 64, 256, 0, stream>>>(h1, agg, wt2h, wt2l, b2, h2);

    // pooling + classifier
    k_pool<<<NG, 256, 0, stream>>>(h2, batch, pool);
    k_final<<<(NG * 10 + 255) / 256, 256, 0, stream>>>(pool, cw, cb, out);
}